// Round 5
// baseline (578.037 us; speedup 1.0000x reference)
//
#include <hip/hip_runtime.h>
#include <math.h>

#define LNUM 3
#define ENUM 8
#define BSZ 256
#define NSZ 1024
#define DSZ 512
#define SSZ 128   // DS

typedef float f32x4 __attribute__((ext_vector_type(4)));

// ============ generic 64x128 GEMM partial tile ============
// C[64][128] = A[64][KC] @ B[KC][128]; 256 threads.
// A row-major (lda), staged transposed into LDS; B row-major (ldb).
template <int KC>
__device__ __forceinline__ void gemm_tile(
    const float* __restrict__ A, int lda,
    const float* __restrict__ B, int ldb,
    float* __restrict__ C, int ldc, int t)
{
    __shared__ float As[32][68];   // [k][b], padded
    __shared__ float Bs[32][128];  // [k][n]

    const int sx = t & 31;         // n-quad: n = sx*4
    const int ty = t >> 5;         // 0..7: b-rows ty*8..+7
    const int brow = t >> 2;       // staging A: 64 rows
    const int kq = t & 3;          // staging A: k-quad group
    const int krow = t >> 3;       // staging B: 32 rows
    const int sq = t & 7;          // staging B: 8 col groups of 16

    f32x4 acc[8];
    #pragma unroll
    for (int r = 0; r < 8; ++r) acc[r] = (f32x4){0.f, 0.f, 0.f, 0.f};

    for (int ks = 0; ks < KC; ks += 32) {
        __syncthreads();
        // stage A transposed: As[k][b]
        const f32x4 av0 = *(const f32x4*)(A + (size_t)brow * lda + ks + kq * 8);
        const f32x4 av1 = *(const f32x4*)(A + (size_t)brow * lda + ks + kq * 8 + 4);
        As[kq * 8 + 0][brow] = av0.x; As[kq * 8 + 1][brow] = av0.y;
        As[kq * 8 + 2][brow] = av0.z; As[kq * 8 + 3][brow] = av0.w;
        As[kq * 8 + 4][brow] = av1.x; As[kq * 8 + 5][brow] = av1.y;
        As[kq * 8 + 6][brow] = av1.z; As[kq * 8 + 7][brow] = av1.w;
        // stage B direct
        const float* Bp = B + (size_t)(ks + krow) * ldb + sq * 16;
        *(f32x4*)&Bs[krow][sq * 16 + 0]  = *(const f32x4*)(Bp + 0);
        *(f32x4*)&Bs[krow][sq * 16 + 4]  = *(const f32x4*)(Bp + 4);
        *(f32x4*)&Bs[krow][sq * 16 + 8]  = *(const f32x4*)(Bp + 8);
        *(f32x4*)&Bs[krow][sq * 16 + 12] = *(const f32x4*)(Bp + 12);
        __syncthreads();

        #pragma unroll
        for (int k = 0; k < 32; ++k) {
            const f32x4 a0 = *(const f32x4*)&As[k][ty * 8];
            const f32x4 a1 = *(const f32x4*)&As[k][ty * 8 + 4];
            const f32x4 bb = *(const f32x4*)&Bs[k][sx * 4];
            acc[0] += bb * a0.x; acc[1] += bb * a0.y;
            acc[2] += bb * a0.z; acc[3] += bb * a0.w;
            acc[4] += bb * a1.x; acc[5] += bb * a1.y;
            acc[6] += bb * a1.z; acc[7] += bb * a1.w;
        }
    }
    #pragma unroll
    for (int r = 0; r < 8; ++r)
        *(f32x4*)(C + (size_t)(ty * 8 + r) * ldc + sx * 4) = acc[r];
}

// ============ K1: G1 partials (dense h@Bin[e]) + gating ============
// grid = 256 G1 blocks + 4 gating blocks, 256 threads.
__global__ __launch_bounds__(256) void k1_g1_gate(
    const float* __restrict__ h,      // [256][512]
    const float* __restrict__ Bin_l,  // [8][512][128]
    const float* __restrict__ Wg_l,   // [512][8]
    const float* __restrict__ bg_l,   // [8]
    float* __restrict__ g1p,          // [8kc][8e][256][128]
    float* __restrict__ gates,        // [256][8]
    float* __restrict__ acc_probs,    // [8]
    float* __restrict__ acc_sel)      // [8]
{
    const int bid = blockIdx.x;
    const int t = threadIdx.x;

    if (bid < 256) {
        const int kc = bid & 7;
        const int bt = (bid >> 3) & 3;
        const int e  = bid >> 5;
        gemm_tile<64>(
            h + (size_t)(bt * 64) * DSZ + kc * 64, DSZ,
            Bin_l + (size_t)e * DSZ * SSZ + (size_t)(kc * 64) * SSZ, SSZ,
            g1p + ((size_t)(kc * 8 + e) * BSZ + bt * 64) * SSZ, SSZ, t);
        return;
    }

    // gating: block handles 64 tokens, each wave 16
    __shared__ float lt[4][8];
    const int wave = t >> 6, lane = t & 63;
    const int e = lane >> 3, dg = lane & 7;
    const int b0 = (bid - 256) * 64 + wave * 16;
    for (int i = 0; i < 16; ++i) {
        const int b = b0 + i;
        float p = 0.f;
        #pragma unroll 8
        for (int j = 0; j < 64; ++j) {
            const int d = dg + 8 * j;
            p = fmaf(h[b * DSZ + d], Wg_l[d * ENUM + e], p);
        }
        p += __shfl_down(p, 4, 8);
        p += __shfl_down(p, 2, 8);
        p += __shfl_down(p, 1, 8);
        if (dg == 0) lt[wave][e] = p + bg_l[e];
        if (lane == 0) {
            float probs[ENUM];
            float mx = lt[wave][0];
            for (int k = 1; k < ENUM; ++k) mx = fmaxf(mx, lt[wave][k]);
            float ss = 0.f;
            for (int k = 0; k < ENUM; ++k) { probs[k] = expf(lt[wave][k] - mx); ss += probs[k]; }
            const float sinv = 1.f / ss;
            for (int k = 0; k < ENUM; ++k) probs[k] *= sinv;
            int i0 = 0;
            for (int k = 1; k < ENUM; ++k) if (probs[k] > probs[i0]) i0 = k;
            int i1 = -1;
            for (int k = 0; k < ENUM; ++k) {
                if (k == i0) continue;
                if (i1 < 0 || probs[k] > probs[i1]) i1 = k;
            }
            const float gs = 1.f / (probs[i0] + probs[i1]);
            for (int k = 0; k < ENUM; ++k) {
                float g = 0.f;
                if (k == i0) g = probs[i0] * gs;
                else if (k == i1) g = probs[i1] * gs;
                gates[b * ENUM + k] = g;
                atomicAdd(&acc_probs[k], probs[k]);
            }
            atomicAdd(&acc_sel[i0], 1.0f);
            atomicAdd(&acc_sel[i1], 1.0f);
        }
    }
}

// ============ K1b: combine G1 partials -> gated s_new + out_states ============
// grid = 256 blocks x 256 threads; one f32x4 quad per thread.
__global__ __launch_bounds__(256) void k1b_combine(
    const float* __restrict__ g1p,     // [8][8][256][128]
    const float* __restrict__ states_l,// [8][256][128]
    const float* __restrict__ A_l,     // [8][128]
    const float* __restrict__ gates,   // [256][8]
    float* __restrict__ sng,           // [8][256][128] gated s_new
    float* __restrict__ out_states_l)  // [8][256][128]
{
    const int q = blockIdx.x * 256 + threadIdx.x;   // quad index, 65536 total
    const int e = q >> 13;
    const int rem = q & 8191;
    const int b = rem >> 5;
    const int sq = rem & 31;

    f32x4 sum = (f32x4){0.f, 0.f, 0.f, 0.f};
    #pragma unroll
    for (int kc = 0; kc < 8; ++kc)
        sum += *(const f32x4*)(g1p + (size_t)kc * 262144 + (size_t)q * 4);

    const f32x4 av = *(const f32x4*)(A_l + e * SSZ + sq * 4);
    f32x4 decay;
    decay.x = 1.f / (1.f + expf(-av.x));
    decay.y = 1.f / (1.f + expf(-av.y));
    decay.z = 1.f / (1.f + expf(-av.z));
    decay.w = 1.f / (1.f + expf(-av.w));

    const f32x4 stq = *(const f32x4*)(states_l + (size_t)q * 4);
    const f32x4 snew = decay * stq + sum;
    const float ge = gates[b * ENUM + e];

    *(f32x4*)(sng + (size_t)q * 4) = snew * ge;
    *(f32x4*)(out_states_l + (size_t)q * 4) = (ge > 0.f) ? snew : stq;
}

// ============ K2: G2 partials: (g*s_new)[e] @ Cout[e] ============
// grid = 128 blocks (e8 x bt4 x dt4), 256 threads.
__global__ __launch_bounds__(256) void k2_g2(
    const float* __restrict__ sng,    // [8][256][128]
    const float* __restrict__ Cout_l, // [8][128][512]
    float* __restrict__ g2p)          // [8e][256][512]
{
    const int bid = blockIdx.x;
    const int e  = bid & 7;
    const int bt = (bid >> 3) & 3;
    const int dt = bid >> 5;
    gemm_tile<128>(
        sng + (size_t)e * BSZ * SSZ + (size_t)(bt * 64) * SSZ, SSZ,
        Cout_l + (size_t)e * SSZ * DSZ + dt * 128, DSZ,
        g2p + ((size_t)e * BSZ + bt * 64) * DSZ + dt * 128, DSZ, threadIdx.x);
}

// ============ K3: h update ============
// grid = 128 blocks x 256 threads; one quad per thread over [256][512].
__global__ __launch_bounds__(256) void k3_hupd(
    const float* __restrict__ h_in,   // [256][512]
    const float* __restrict__ g2p,    // [8][256][512]
    const float* __restrict__ Dsk_l,  // [8][512]
    const float* __restrict__ gates,  // [256][8]
    float* __restrict__ h_out)        // [256][512]
{
    const int q = blockIdx.x * 256 + threadIdx.x;   // 32768 quads
    const int b = q >> 7;
    const int dq = q & 127;
    const int d = dq * 4;

    f32x4 acc = (f32x4){0.f, 0.f, 0.f, 0.f};
    f32x4 dsum = (f32x4){0.f, 0.f, 0.f, 0.f};
    #pragma unroll
    for (int e = 0; e < ENUM; ++e) {
        acc += *(const f32x4*)(g2p + ((size_t)e * BSZ + b) * DSZ + d);
        dsum += *(const f32x4*)(Dsk_l + e * DSZ + d) * gates[b * ENUM + e];
    }
    const f32x4 hq = *(const f32x4*)(h_in + (size_t)b * DSZ + d);
    *(f32x4*)(h_out + (size_t)b * DSZ + d) = hq + acc + hq * dsum;
}

// ============ K4: q partials: h @ Wq ============
// grid = 64 blocks (kc4 x bt4 x dt4), 256 threads.
__global__ __launch_bounds__(256) void k4_q(
    const float* __restrict__ h,   // [256][512]
    const float* __restrict__ Wq,  // [512][512]
    float* __restrict__ qp)        // [4kc][256][512]
{
    const int bid = blockIdx.x;
    const int kc = bid & 3;
    const int bt = (bid >> 2) & 3;
    const int dt = bid >> 4;
    gemm_tile<128>(
        h + (size_t)(bt * 64) * DSZ + kc * 128, DSZ,
        Wq + (size_t)(kc * 128) * DSZ + dt * 128, DSZ,
        qp + ((size_t)(kc * 256) + bt * 64) * DSZ + dt * 128, DSZ, threadIdx.x);
}

// ============ logits + q-combine + lb_loss ============
// grid = (8, 256), 256 threads (4 waves), wave handles 32 n's.
__global__ __launch_bounds__(256) void logits_kernel(
    const float* __restrict__ qp,       // [4][256][512]
    const float* __restrict__ bq,       // [512]
    const float* __restrict__ node_emb, // [256][1024][512]
    float* __restrict__ logits,
    const float* __restrict__ acc, float* __restrict__ loss_out)
{
    const int b = blockIdx.y;
    const int wave = threadIdx.x >> 6;
    const int lane = threadIdx.x & 63;

    __shared__ float q_s[DSZ];
    if (threadIdx.x < 128) {
        const int d = threadIdx.x * 4;
        f32x4 qv = *(const f32x4*)(bq + d);
        #pragma unroll
        for (int kc = 0; kc < 4; ++kc)
            qv += *(const f32x4*)(qp + ((size_t)(kc * 256) + b) * DSZ + d);
        *(f32x4*)&q_s[d] = qv;
    }
    __syncthreads();

    if (blockIdx.x == 0 && blockIdx.y == 0 && threadIdx.x == 0) {
        float lb = 0.f;
        for (int l = 0; l < LNUM; ++l)
            for (int e = 0; e < ENUM; ++e) {
                const float mp = acc[l * 16 + e] * (1.0f / BSZ);
                const float ms = acc[l * 16 + 8 + e] * (1.0f / BSZ);
                lb += (float)ENUM * mp * ms;
            }
        loss_out[0] = lb;
    }

    const f32x4 q0 = *(const f32x4*)&q_s[lane * 4];
    const f32x4 q1 = *(const f32x4*)&q_s[256 + lane * 4];
    const float scale = 0.04419417382415922f;  // 1/sqrt(512)

    const int n0 = blockIdx.x * 128 + wave * 32;
    #pragma unroll 2
    for (int i = 0; i < 32; ++i) {
        const int n = n0 + i;
        const float* r = node_emb + ((size_t)b * NSZ + n) * DSZ;
        const f32x4 a0 = __builtin_nontemporal_load((const f32x4*)(r) + lane);
        const f32x4 a1 = __builtin_nontemporal_load((const f32x4*)(r) + lane + 64);
        float dot = a0.x * q0.x + a0.y * q0.y + a0.z * q0.z + a0.w * q0.w
                  + a1.x * q1.x + a1.y * q1.y + a1.z * q1.z + a1.w * q1.w;
        for (int off = 32; off; off >>= 1) dot += __shfl_down(dot, off, 64);
        if (lane == 0) logits[b * NSZ + n] = dot * scale;
    }
}

extern "C" void kernel_launch(void* const* d_in, const int* in_sizes, int n_in,
                              void* d_out, int out_size, void* d_ws, size_t ws_size,
                              hipStream_t stream) {
    const float* token    = (const float*)d_in[0];  // B,1,D
    const float* node_emb = (const float*)d_in[1];  // B,N,D
    const float* states   = (const float*)d_in[2];  // L,E,B,DS
    const float* Wg       = (const float*)d_in[3];  // L,D,E
    const float* bg       = (const float*)d_in[4];  // L,E
    const float* A        = (const float*)d_in[5];  // L,E,DS
    const float* Bin      = (const float*)d_in[6];  // L,E,D,DS
    const float* Cout     = (const float*)d_in[7];  // L,E,DS,D
    const float* Dsk      = (const float*)d_in[8];  // L,E,D
    const float* Wq       = (const float*)d_in[9];  // D,D
    const float* bq       = (const float*)d_in[10]; // D

    float* out_logits = (float*)d_out;                                  // B*N
    float* out_states = out_logits + (size_t)BSZ * NSZ;                 // L*E*B*DS
    float* out_loss   = out_states + (size_t)LNUM * ENUM * BSZ * SSZ;   // 1

    // workspace layout (floats)
    float* ws_g1p   = (float*)d_ws;            // 8*8*256*128 = 2097152
    float* ws_g2p   = ws_g1p + 2097152;        // 8*256*512   = 1048576
    float* ws_qp    = ws_g2p + 1048576;        // 4*256*512   = 524288
    float* ws_sng   = ws_qp  + 524288;         // 8*256*128   = 262144
    float* ws_h     = ws_sng + 262144;         // 256*512     = 131072
    float* ws_gates = ws_h   + 131072;         // 256*8       = 2048
    float* ws_acc   = ws_gates + 2048;         // 3*16        = 48

    (void)hipMemsetAsync(ws_acc, 0, sizeof(float) * LNUM * 16, stream);

    const float* h_cur = token;   // token[:,0,:] contiguous [256][512]
    for (int l = 0; l < LNUM; ++l) {
        const float* Bin_l = Bin + (size_t)l * ENUM * DSZ * SSZ;
        const float* Cou_l = Cout + (size_t)l * ENUM * SSZ * DSZ;
        const float* st_l  = states + (size_t)l * ENUM * BSZ * SSZ;
        float* os_l        = out_states + (size_t)l * ENUM * BSZ * SSZ;

        k1_g1_gate<<<260, 256, 0, stream>>>(
            h_cur, Bin_l,
            Wg + (size_t)l * DSZ * ENUM, bg + (size_t)l * ENUM,
            ws_g1p, ws_gates, ws_acc + l * 16, ws_acc + l * 16 + 8);

        k1b_combine<<<256, 256, 0, stream>>>(
            ws_g1p, st_l, A + (size_t)l * ENUM * SSZ, ws_gates, ws_sng, os_l);

        k2_g2<<<128, 256, 0, stream>>>(ws_sng, Cou_l, ws_g2p);

        k3_hupd<<<128, 256, 0, stream>>>(
            h_cur, ws_g2p, Dsk + (size_t)l * ENUM * DSZ, ws_gates, ws_h);

        h_cur = ws_h;
    }

    k4_q<<<64, 256, 0, stream>>>(ws_h, Wq, ws_qp);

    dim3 lg(NSZ / 128, BSZ);
    logits_kernel<<<lg, 256, 0, stream>>>(ws_qp, bq, node_emb, out_logits, ws_acc, out_loss);
}

// Round 7
// 184.246 us; speedup vs baseline: 3.1373x; 3.1373x over previous
//
#include <hip/hip_runtime.h>
#include <math.h>

#define LNUM 3
#define ENUM 8
#define BSZ 256
#define NSZ 1024
#define DSZ 512
#define SSZ 128   // DS

typedef float f32x4 __attribute__((ext_vector_type(4)));

// ---------------- per-layer kernel, 2 blocks per token ----------------
// grid = 512 (b = bid&255, slot k = bid>>8), block = 512 threads (8 waves).
// Block k handles selected-expert slot k (k=0 -> i0, k=1 -> i1):
//   h reconstruct (h_base + y_in pair), gating (redundant), s_new for its
//   expert, out_states share, y_k pre-scaled by gate -> y_out[k].
__global__ __launch_bounds__(512, 4) void layer2_kernel(
    const float* __restrict__ h_base,  // [B][D] (token or hbuf)
    const float* __restrict__ y_in,    // [2][B][D] prescaled, or null (l=0)
    float* __restrict__ h_store,       // [B][D] or null: store reconstructed h
    float* __restrict__ y_out,         // [2][B][D]
    const float* __restrict__ Wg_l,    // [D][E]
    const float* __restrict__ bg_l,    // [E]
    const float* __restrict__ A_l,     // [E][DS]
    const float* __restrict__ Bin_l,   // [E][D][DS]
    const float* __restrict__ Cou_l,   // [E][DS][D]
    const float* __restrict__ Dsk_l,   // [E][D]
    const float* __restrict__ st_l,    // [E][B][DS]
    float* __restrict__ os_l,          // [E][B][DS]
    float* __restrict__ acc_probs,     // [E]
    float* __restrict__ acc_sel)       // [E]
{
    const int b = blockIdx.x & 255;
    const int k = blockIdx.x >> 8;
    const int t = threadIdx.x;
    const int wave = t >> 6;
    const int lane = t & 63;

    __shared__ float h_s[DSZ];
    __shared__ float snew_s[SSZ];
    __shared__ float logit_s[ENUM];
    __shared__ f32x4 part4[512];
    float* part = (float*)part4;

    // ---- Phase A: reconstruct h = h_base + y0 + y1 (prescaled) ----
    if (t < 128) {
        f32x4 hq = ((const f32x4*)(h_base + (size_t)b * DSZ))[t];
        if (y_in) {
            hq += ((const f32x4*)(y_in + (size_t)b * DSZ))[t];
            hq += ((const f32x4*)(y_in + (size_t)(BSZ + b) * DSZ))[t];
        }
        ((f32x4*)h_s)[t] = hq;
        if (h_store && k == 0) ((f32x4*)(h_store + (size_t)b * DSZ))[t] = hq;
    }
    __syncthreads();

    // ---- gating: wave w computes expert w's logit ----
    {
        float p = 0.f;
        #pragma unroll
        for (int i = 0; i < 8; ++i) {
            const int d = lane + i * 64;
            p = fmaf(h_s[d], Wg_l[d * ENUM + wave], p);
        }
        for (int off = 32; off; off >>= 1) p += __shfl_down(p, off, 64);
        if (lane == 0) logit_s[wave] = p + bg_l[wave];
    }
    __syncthreads();

    // ---- softmax + top2, redundant per thread (identical results) ----
    float probs[ENUM];
    float mx = logit_s[0];
    for (int e = 1; e < ENUM; ++e) mx = fmaxf(mx, logit_s[e]);
    float ssum = 0.f;
    for (int e = 0; e < ENUM; ++e) { probs[e] = expf(logit_s[e] - mx); ssum += probs[e]; }
    const float sinv = 1.f / ssum;
    for (int e = 0; e < ENUM; ++e) probs[e] *= sinv;

    int i0 = 0;
    for (int e = 1; e < ENUM; ++e) if (probs[e] > probs[i0]) i0 = e;
    int i1 = -1;
    for (int e = 0; e < ENUM; ++e) {
        if (e == i0) continue;
        if (i1 < 0 || probs[e] > probs[i1]) i1 = e;
    }
    float g0 = probs[i0], g1 = probs[i1];
    const float ginv = 1.f / (g0 + g1);
    g0 *= ginv; g1 *= ginv;

    if (k == 0 && t < ENUM) {
        atomicAdd(&acc_probs[t], probs[t]);
        atomicAdd(&acc_sel[t], (t == i0 || t == i1) ? 1.0f : 0.0f);
    }

    const int esel = k ? i1 : i0;
    const float gsel = k ? g1 : g0;

    // ---- s_new partials: t -> (kc = t>>5 in 0..15, sq = t&31) ----
    {
        const int kc = t >> 5, sq = t & 31;
        const float* Bp = Bin_l + (size_t)esel * DSZ * SSZ + sq * 4;
        const int d0 = kc * 32;
        f32x4 a4 = {0.f, 0.f, 0.f, 0.f};
        #pragma unroll
        for (int d = 0; d < 32; ++d)
            a4 += *(const f32x4*)(Bp + (size_t)(d0 + d) * SSZ) * h_s[d0 + d];
        part4[t] = a4;   // [kc][sq]
    }
    __syncthreads();

    // combine + decay -> snew_s
    if (t < SSZ) {
        float sum = 0.f;
        #pragma unroll
        for (int kc = 0; kc < 16; ++kc) sum += part[kc * 128 + t];
        const float a = A_l[esel * SSZ + t];
        const float decay = 1.f / (1.f + expf(-a));
        snew_s[t] = decay * st_l[((size_t)esel * BSZ + b) * SSZ + t] + sum;
    }
    __syncthreads();

    // ---- out_states: slot write + passthrough for owned expert range ----
    if (t < SSZ) os_l[((size_t)esel * BSZ + b) * SSZ + t] = snew_s[t];
    {
        const int e = k * 4 + (t >> 7);   // 4 experts owned per block
        const int s = t & 127;
        if (e != i0 && e != i1)
            os_l[((size_t)e * BSZ + b) * SSZ + s] = st_l[((size_t)e * BSZ + b) * SSZ + s];
    }

    // ---- y partials: t -> (sc = t>>7 in 0..3, dq = t&127) ----
    {
        const int sc = t >> 7, dq = t & 127;
        const float* Cp = Cou_l + (size_t)esel * SSZ * DSZ + dq * 4;
        const int s0 = sc * 32;
        f32x4 a4 = {0.f, 0.f, 0.f, 0.f};
        #pragma unroll
        for (int s = 0; s < 32; ++s)
            a4 += *(const f32x4*)(Cp + (size_t)(s0 + s) * DSZ) * snew_s[s0 + s];
        part4[sc * 128 + dq] = a4;
    }
    __syncthreads();

    // combine: y_out[k][b] = gsel * (sum partials + h*Dsk[esel])
    if (t < 128) {
        f32x4 yq = part4[t] + part4[128 + t] + part4[256 + t] + part4[384 + t];
        const f32x4 hq = ((const f32x4*)h_s)[t];
        const f32x4 dk = *(const f32x4*)(Dsk_l + esel * DSZ + t * 4);
        yq += hq * dk;
        ((f32x4*)(y_out + (size_t)(k * BSZ + b) * DSZ))[t] = yq * gsel;
    }
}

// ---------------- q kernel: q = h3 @ Wq + bq ----------------
// grid = 512 (b = bid&255, column-half k = bid>>8), block = 512 threads.
__global__ __launch_bounds__(512, 4) void q2_kernel(
    const float* __restrict__ h_base,  // [B][D] (hbuf: h2 input)
    const float* __restrict__ y_in,    // [2][B][D] prescaled layer-2 y pair
    const float* __restrict__ Wq,      // [D][D]
    const float* __restrict__ bq,      // [D]
    float* __restrict__ q_out)         // [B][D]
{
    const int b = blockIdx.x & 255;
    const int k = blockIdx.x >> 8;
    const int t = threadIdx.x;

    __shared__ float h_s[DSZ];
    __shared__ f32x4 part4[512];

    if (t < 128) {
        f32x4 hq = ((const f32x4*)(h_base + (size_t)b * DSZ))[t]
                 + ((const f32x4*)(y_in + (size_t)b * DSZ))[t]
                 + ((const f32x4*)(y_in + (size_t)(BSZ + b) * DSZ))[t];
        ((f32x4*)h_s)[t] = hq;
    }
    __syncthreads();

    {
        const int kc = t >> 6, cq = t & 63;   // 8 K-chunks x 64 col-quads
        const float* Wp = Wq + k * 256 + cq * 4;
        const int d0 = kc * 64;
        f32x4 a4 = {0.f, 0.f, 0.f, 0.f};
        #pragma unroll
        for (int i = 0; i < 64; ++i)
            a4 += *(const f32x4*)(Wp + (size_t)(d0 + i) * DSZ) * h_s[d0 + i];
        part4[kc * 64 + cq] = a4;
    }
    __syncthreads();

    if (t < 64) {
        f32x4 qq = *(const f32x4*)(bq + k * 256 + t * 4);
        #pragma unroll
        for (int kc = 0; kc < 8; ++kc) qq += part4[kc * 64 + t];
        ((f32x4*)(q_out + (size_t)b * DSZ))[k * 64 + t] = qq;
    }
}

// ---------------- logits[b,n] = q[b] . node_emb[b,n,:] / sqrt(D) ----------------
// grid = (8, B), block = 256 (4 waves). Each wave: 32 n's, one row-dot each.
// Block (0,0) thread 0 additionally finishes lb_loss.
__global__ __launch_bounds__(256) void logits_kernel(
    const float* __restrict__ q, const float* __restrict__ node_emb,
    float* __restrict__ logits,
    const float* __restrict__ acc, float* __restrict__ loss_out)
{
    const int b = blockIdx.y;
    const int wave = threadIdx.x >> 6;
    const int lane = threadIdx.x & 63;

    if (blockIdx.x == 0 && blockIdx.y == 0 && threadIdx.x == 0) {
        float lb = 0.f;
        for (int l = 0; l < LNUM; ++l)
            for (int e = 0; e < ENUM; ++e) {
                const float mp = acc[(l * 2 + 0) * ENUM + e] * (1.0f / BSZ);
                const float ms = acc[(l * 2 + 1) * ENUM + e] * (1.0f / BSZ);
                lb += (float)ENUM * mp * ms;
            }
        loss_out[0] = lb;
    }

    const f32x4* q4 = (const f32x4*)(q + b * DSZ);
    const f32x4 q0 = q4[lane];
    const f32x4 q1 = q4[lane + 64];
    const float scale = 0.04419417382415922f;  // 1/sqrt(512)

    const int n0 = blockIdx.x * 128 + wave * 32;
    #pragma unroll 2
    for (int i = 0; i < 32; ++i) {
        const int n = n0 + i;
        const f32x4* r = (const f32x4*)(node_emb + ((size_t)b * NSZ + n) * DSZ);
        const f32x4 a0 = __builtin_nontemporal_load(&r[lane]);
        const f32x4 a1 = __builtin_nontemporal_load(&r[lane + 64]);
        float dot = a0.x * q0.x + a0.y * q0.y + a0.z * q0.z + a0.w * q0.w
                  + a1.x * q1.x + a1.y * q1.y + a1.z * q1.z + a1.w * q1.w;
        for (int off = 32; off; off >>= 1) dot += __shfl_down(dot, off, 64);
        if (lane == 0) logits[b * NSZ + n] = dot * scale;
    }
}

extern "C" void kernel_launch(void* const* d_in, const int* in_sizes, int n_in,
                              void* d_out, int out_size, void* d_ws, size_t ws_size,
                              hipStream_t stream) {
    const float* token    = (const float*)d_in[0];  // B,1,D
    const float* node_emb = (const float*)d_in[1];  // B,N,D
    const float* states   = (const float*)d_in[2];  // L,E,B,DS
    const float* Wg       = (const float*)d_in[3];  // L,D,E
    const float* bg       = (const float*)d_in[4];  // L,E
    const float* A        = (const float*)d_in[5];  // L,E,DS
    const float* Bin      = (const float*)d_in[6];  // L,E,D,DS
    const float* Cout     = (const float*)d_in[7];  // L,E,DS,D
    const float* Dsk      = (const float*)d_in[8];  // L,E,D
    const float* Wq       = (const float*)d_in[9];  // D,D
    const float* bq       = (const float*)d_in[10]; // D

    float* out_logits = (float*)d_out;                                  // B*N
    float* out_states = out_logits + (size_t)BSZ * NSZ;                 // L*E*B*DS
    float* out_loss   = out_states + (size_t)LNUM * ENUM * BSZ * SSZ;   // 1

    // workspace layout (floats)
    float* ws_q   = (float*)d_ws;                     // B*D
    float* ws_acc = ws_q + (size_t)BSZ * DSZ;         // 64
    float* hbuf0  = ws_acc + 64;                      // B*D
    float* hbuf1  = hbuf0 + (size_t)BSZ * DSZ;        // B*D
    float* ybufA  = hbuf1 + (size_t)BSZ * DSZ;        // 2*B*D
    float* ybufB  = ybufA + (size_t)2 * BSZ * DSZ;    // 2*B*D

    (void)hipMemsetAsync(ws_acc, 0, sizeof(float) * LNUM * 16, stream);

    const float* y_ins[LNUM]   = { nullptr, ybufA, ybufB };
    float*       h_stores[LNUM]= { nullptr, hbuf0, hbuf1 };
    float*       y_outs[LNUM]  = { ybufA,   ybufB, ybufA };
    const float* h_bases[LNUM] = { token,   token, hbuf0 };

    for (int l = 0; l < LNUM; ++l) {
        layer2_kernel<<<512, 512, 0, stream>>>(
            h_bases[l], y_ins[l], h_stores[l], y_outs[l],
            Wg  + (size_t)l * DSZ * ENUM,
            bg  + (size_t)l * ENUM,
            A   + (size_t)l * ENUM * SSZ,
            Bin + (size_t)l * ENUM * DSZ * SSZ,
            Cout+ (size_t)l * ENUM * SSZ * DSZ,
            Dsk + (size_t)l * ENUM * DSZ,
            states + (size_t)l * ENUM * BSZ * SSZ,
            out_states + (size_t)l * ENUM * BSZ * SSZ,
            ws_acc + (l * 2 + 0) * ENUM,
            ws_acc + (l * 2 + 1) * ENUM);
    }

    // h3 = hbuf1 + ybufA pair (layer 2 wrote h2 into hbuf1, y-pair into ybufA)
    q2_kernel<<<512, 512, 0, stream>>>(hbuf1, ybufA, Wq, bq, ws_q);

    dim3 lg(NSZ / 128, BSZ);
    logits_kernel<<<lg, 256, 0, stream>>>(ws_q, node_emb, out_logits, ws_acc, out_loss);
}